// Round 13
// baseline (753.544 us; speedup 1.0000x reference)
//
#include <hip/hip_runtime.h>
#include <math.h>

#define LN_EPS 1e-5f
#define COS_EPS 1e-8f

typedef short bf16x8 __attribute__((ext_vector_type(8)));
typedef float f32x4 __attribute__((ext_vector_type(4)));

static __device__ __forceinline__ unsigned short f2bf(float f) {
    unsigned u = __float_as_uint(f);
    u = u + 0x7FFFu + ((u >> 16) & 1u);   // round-to-nearest-even
    return (unsigned short)(u >> 16);
}
static __device__ __forceinline__ float bf2f(short s) {
    return __uint_as_float(((unsigned)(unsigned short)s) << 16);
}

// int8 quantize: clamp(round(f)) to [-127,127], return low byte
static __device__ __forceinline__ unsigned f2i8(float f) {
    int i = (int)rintf(f);
    i = max(-127, min(127, i));
    return (unsigned)i & 0xffu;
}

// 4-way int8 dot: d = a.b + c (per-byte signed). v_dot4_i32_i8 when available.
static __device__ __forceinline__ int dot4i8(int a, int b, int c) {
#if defined(__has_builtin) && __has_builtin(__builtin_amdgcn_sdot4)
    return __builtin_amdgcn_sdot4(a, b, c, false);
#else
    int s = c;
#pragma unroll
    for (int k = 0; k < 4; ++k) {
        int av = (a << (24 - 8 * k)) >> 24;
        int bv = (b << (24 - 8 * k)) >> 24;
        s += av * bv;
    }
    return s;
#endif
}

// load/store EPL bf16 elements per lane as one vector op
template<int EPL>
static __device__ __forceinline__ void loadrow(const short* __restrict__ p, float* r) {
    if constexpr (EPL == 4) {
        short4 v = *reinterpret_cast<const short4*>(p);
        r[0] = bf2f(v.x); r[1] = bf2f(v.y); r[2] = bf2f(v.z); r[3] = bf2f(v.w);
    } else {
        short2 v = *reinterpret_cast<const short2*>(p);
        r[0] = bf2f(v.x); r[1] = bf2f(v.y);
    }
}
template<int EPL>
static __device__ __forceinline__ void storerow(short* __restrict__ p, const float* m) {
    if constexpr (EPL == 4) {
        short4 v;
        v.x = (short)f2bf(m[0]); v.y = (short)f2bf(m[1]);
        v.z = (short)f2bf(m[2]); v.w = (short)f2bf(m[3]);
        *reinterpret_cast<short4*>(p) = v;
    } else {
        short2 v;
        v.x = (short)f2bf(m[0]); v.y = (short)f2bf(m[1]);
        *reinterpret_cast<short2*>(p) = v;
    }
}

// load EPL packed int8 elements per lane as one scalar (zero-extended)
template<int EPL>
static __device__ __forceinline__ int loadpk(const unsigned char* __restrict__ p) {
    if constexpr (EPL == 4) return (int)*reinterpret_cast<const unsigned*>(p);
    else                    return (int)*reinterpret_cast<const unsigned short*>(p);
}

// ---------------- CSR build ----------------
__global__ void count_deg(const int* __restrict__ src, const int* __restrict__ dst,
                          int* __restrict__ deg_src, int* __restrict__ deg_dst, int E) {
    int e = blockIdx.x * blockDim.x + threadIdx.x;
    if (e < E) {
        atomicAdd(&deg_src[src[e]], 1);
        atomicAdd(&deg_dst[dst[e]], 1);
    }
}

__global__ void scan_phase1(const int* __restrict__ degA, const int* __restrict__ degB,
                            int* __restrict__ rpA, int* __restrict__ rpB,
                            int* __restrict__ bsA, int* __restrict__ bsB, int n, int nb) {
    __shared__ int sdata[256];
    int bid = blockIdx.x;
    const int* deg; int* rp; int* bs; int seg;
    if (bid < nb) { deg = degA; rp = rpA; bs = bsA; seg = bid; }
    else          { deg = degB; rp = rpB; bs = bsB; seg = bid - nb; }
    int i = seg * 256 + threadIdx.x;
    int v = (i < n) ? deg[i] : 0;
    sdata[threadIdx.x] = v;
    __syncthreads();
    for (int off = 1; off < 256; off <<= 1) {
        int t = (threadIdx.x >= off) ? sdata[threadIdx.x - off] : 0;
        __syncthreads();
        sdata[threadIdx.x] += t;
        __syncthreads();
    }
    if (i < n) rp[i] = sdata[threadIdx.x] - v;   // exclusive within block
    if (threadIdx.x == 255) bs[seg] = sdata[255];
}

__global__ void scan_phase2(int* __restrict__ bsA, int* __restrict__ bsB, int nb,
                            int* __restrict__ rpA, int* __restrict__ rpB, int n) {
    __shared__ int sdata[256];
    __shared__ int s_carry;
    for (int arr = 0; arr < 2; ++arr) {
        int* bs = arr ? bsB : bsA;
        int* rp = arr ? rpB : rpA;
        if (threadIdx.x == 0) s_carry = 0;
        __syncthreads();
        for (int base = 0; base < nb; base += 256) {
            int i = base + threadIdx.x;
            int v = (i < nb) ? bs[i] : 0;
            sdata[threadIdx.x] = v;
            __syncthreads();
            for (int off = 1; off < 256; off <<= 1) {
                int t = (threadIdx.x >= off) ? sdata[threadIdx.x - off] : 0;
                __syncthreads();
                sdata[threadIdx.x] += t;
                __syncthreads();
            }
            if (i < nb) bs[i] = s_carry + sdata[threadIdx.x] - v;
            __syncthreads();
            if (threadIdx.x == 255) s_carry += sdata[255];
            __syncthreads();
        }
        if (threadIdx.x == 0) rp[n] = s_carry;
        __syncthreads();
    }
}

__global__ void scan_phase3(int* __restrict__ rpA, int* __restrict__ rpB,
                            const int* __restrict__ bsA, const int* __restrict__ bsB,
                            int* __restrict__ curA, int* __restrict__ curB, int n, int nb) {
    int bid = blockIdx.x;
    if (bid < nb) {
        int i = bid * 256 + threadIdx.x;
        if (i < n) { int v = rpA[i] + bsA[bid]; rpA[i] = v; curA[i] = v; }
    } else {
        int seg = bid - nb;
        int i = seg * 256 + threadIdx.x;
        if (i < n) { int v = rpB[i] + bsB[seg]; rpB[i] = v; curB[i] = v; }
    }
}

// src-CSR: CSRS[p] = dst. dst-CSR: SRCd[q] = src. (alpha computed inline later)
__global__ void fill_csr(const int* __restrict__ src, const int* __restrict__ dst,
                         int* __restrict__ cur_src, int* __restrict__ cur_dst,
                         int* __restrict__ CSRS, int* __restrict__ SRCd, int E) {
    int e = blockIdx.x * blockDim.x + threadIdx.x;
    if (e < E) {
        int s = src[e], d = dst[e];
        int p = atomicAdd(&cur_src[s], 1);
        int q = atomicAdd(&cur_dst[d], 1);
        __builtin_nontemporal_store(d, CSRS + p);
        __builtin_nontemporal_store(s, SRCd + q);
    }
}

// ---------------- casts / packing ----------------
__global__ void cast_bf16(const float* __restrict__ X, short* __restrict__ Y, int n4) {
    int i = blockIdx.x * blockDim.x + threadIdx.x;
    if (i >= n4) return;
    float4 v = reinterpret_cast<const float4*>(X)[i];
    short4 o;
    o.x = (short)f2bf(v.x); o.y = (short)f2bf(v.y);
    o.z = (short)f2bf(v.z); o.w = (short)f2bf(v.w);
    reinterpret_cast<short4*>(Y)[i] = o;
}

// Pack W (K x ncols f32, row-major) into per-lane MFMA B-fragment layout
__global__ void pack_w(const float* __restrict__ W, short* __restrict__ Wp,
                       int KT, int NCT_total, int ct_base, int nct_local, int ncols) {
    int idx = blockIdx.x * blockDim.x + threadIdx.x;
    int total = KT * nct_local * 512;
    if (idx >= total) return;
    int j = idx & 7;
    int l = (idx >> 3) & 63;
    int t = idx >> 9;
    int ctl = t % nct_local;
    int kt = t / nct_local;
    int k = kt * 32 + (l >> 4) * 8 + j;
    int col = ctl * 16 + (l & 15);
    float v = (col < ncols) ? W[(size_t)k * ncols + col] : 0.f;
    Wp[(((size_t)kt * NCT_total + ct_base + ctl) * 64 + l) * 8 + j] = (short)f2bf(v);
}

// ------- FUSED kernel: blocks [0,ngemm) = MFMA GEMM (+LN epilogue),
//         blocks [ngemm, ngemm+nmu) = mu_norm (int8 normalized means).
// Both consume only the layer input Xb -> independent, co-resident waves
// fill each other's latency bubbles (GEMM occ 16%, mu gather-latency-bound).
// MODE 1: per-head LN (heads of 64 cols), rest -> XBb. MODE 2: LN over 40 cols.
template<int KT, int NCT, int NCT_A, int MODE, int EPL>
__global__ __launch_bounds__(512) void fused_gemm_mu(const short* __restrict__ Xb,
                                                     const short* __restrict__ Wp,
                                                     short* __restrict__ XL,
                                                     short* __restrict__ XBb,
                                                     const float* __restrict__ g,
                                                     const float* __restrict__ b,
                                                     const int* __restrict__ rp,
                                                     const int* __restrict__ CSRS,
                                                     unsigned char* __restrict__ MUn,
                                                     float* __restrict__ NRM,
                                                     int N, int ngemm) {
    __shared__ short bsm[NCT * 512];
    int tid = threadIdx.x;
    int lane = tid & 63;
    if ((int)blockIdx.x < ngemm) {
        // ---------------- GEMM body ----------------
        const int K = KT * 32;
        int wave = tid >> 6;
        size_t row0 = ((size_t)blockIdx.x * 8 + wave) * 16;
        bool active = row0 < (size_t)N;
        const short* arow = Xb + (row0 + (lane & 15)) * K + (lane >> 4) * 8;

        f32x4 acc[NCT];
#pragma unroll
        for (int ct = 0; ct < NCT; ++ct) {
            f32x4 z = {0.f, 0.f, 0.f, 0.f};
            acc[ct] = z;
        }

#pragma unroll 1
        for (int kt = 0; kt < KT; ++kt) {
            __syncthreads();
            const int4* wsrc = reinterpret_cast<const int4*>(Wp + (size_t)kt * NCT * 512);
            int4* wdst = reinterpret_cast<int4*>(bsm);
            for (int i = tid; i < NCT * 64; i += 512) wdst[i] = wsrc[i];
            __syncthreads();
            if (active) {
                bf16x8 a = *reinterpret_cast<const bf16x8*>(arow + kt * 32);
#pragma unroll
                for (int ct = 0; ct < NCT; ++ct) {
                    bf16x8 bv = *reinterpret_cast<const bf16x8*>(bsm + ct * 512 + lane * 8);
                    acc[ct] = __builtin_amdgcn_mfma_f32_16x16x32_bf16(a, bv, acc[ct], 0, 0, 0);
                }
            }
        }
        if (!active) return;

        int c0 = lane & 15;
        int r0 = (lane >> 4) * 4;
        if constexpr (MODE == 1) {
            float gg[4], bv[4];
#pragma unroll
            for (int m = 0; m < 4; ++m) {
                gg[m] = g[m * 16 + c0];
                bv[m] = b[m * 16 + c0];
            }
#pragma unroll
            for (int h = 0; h < NCT_A / 4; ++h) {
#pragma unroll
                for (int j = 0; j < 4; ++j) {
                    float s = acc[4*h+0][j] + acc[4*h+1][j] + acc[4*h+2][j] + acc[4*h+3][j];
                    s += __shfl_xor(s, 1, 64); s += __shfl_xor(s, 2, 64);
                    s += __shfl_xor(s, 4, 64); s += __shfl_xor(s, 8, 64);
                    float mu_ = s * 0.015625f;
                    float d0 = acc[4*h+0][j] - mu_, d1 = acc[4*h+1][j] - mu_;
                    float d2 = acc[4*h+2][j] - mu_, d3 = acc[4*h+3][j] - mu_;
                    float s2 = d0*d0 + d1*d1 + d2*d2 + d3*d3;
                    s2 += __shfl_xor(s2, 1, 64); s2 += __shfl_xor(s2, 2, 64);
                    s2 += __shfl_xor(s2, 4, 64); s2 += __shfl_xor(s2, 8, 64);
                    float rs = rsqrtf(s2 * 0.015625f + LN_EPS);
                    size_t row = row0 + r0 + j;
                    short* rowp = XL + row * 256 + c0;
                    rowp[(4*h+0)*16] = (short)f2bf(d0 * rs * gg[0] + bv[0]);
                    rowp[(4*h+1)*16] = (short)f2bf(d1 * rs * gg[1] + bv[1]);
                    rowp[(4*h+2)*16] = (short)f2bf(d2 * rs * gg[2] + bv[2]);
                    rowp[(4*h+3)*16] = (short)f2bf(d3 * rs * gg[3] + bv[3]);
                }
            }
#pragma unroll
            for (int ct = NCT_A; ct < NCT; ++ct) {
#pragma unroll
                for (int j = 0; j < 4; ++j) {
                    size_t row = row0 + r0 + j;
                    XBb[row * 256 + (ct - NCT_A) * 16 + c0] = (short)f2bf(acc[ct][j]);
                }
            }
        } else if constexpr (MODE == 2) {
            bool valid[NCT];
            float gg[NCT], bv[NCT];
#pragma unroll
            for (int ct = 0; ct < NCT; ++ct) {
                int col = ct * 16 + c0;
                valid[ct] = col < 40;
                gg[ct] = valid[ct] ? g[col] : 0.f;
                bv[ct] = valid[ct] ? b[col] : 0.f;
            }
#pragma unroll
            for (int j = 0; j < 4; ++j) {
                float s = 0.f;
#pragma unroll
                for (int ct = 0; ct < NCT; ++ct) s += valid[ct] ? acc[ct][j] : 0.f;
                s += __shfl_xor(s, 1, 64); s += __shfl_xor(s, 2, 64);
                s += __shfl_xor(s, 4, 64); s += __shfl_xor(s, 8, 64);
                float mu_ = s * 0.025f;
                float d[NCT];
                float s2 = 0.f;
#pragma unroll
                for (int ct = 0; ct < NCT; ++ct) {
                    d[ct] = valid[ct] ? (acc[ct][j] - mu_) : 0.f;
                    s2 += d[ct] * d[ct];
                }
                s2 += __shfl_xor(s2, 1, 64); s2 += __shfl_xor(s2, 2, 64);
                s2 += __shfl_xor(s2, 4, 64); s2 += __shfl_xor(s2, 8, 64);
                float rs = rsqrtf(s2 * 0.025f + LN_EPS);
                size_t row = row0 + r0 + j;
#pragma unroll
                for (int ct = 0; ct < NCT; ++ct) {
                    int col = ct * 16 + c0;
                    if (valid[ct]) XL[row * 40 + col] = (short)f2bf(d[ct] * rs * gg[ct] + bv[ct]);
                }
            }
        }
    } else {
        // ---------------- mu_norm body (8 nodes/block) ----------------
        int n = ((int)blockIdx.x - ngemm) * 8 + (tid >> 6);
        if (n >= N) return;
        const int Fin = EPL * 64;
        int j0 = rp[n], j1 = rp[n + 1];
        float acc[EPL];
#pragma unroll
        for (int k = 0; k < EPL; ++k) acc[k] = 0.f;
        int j = j0;
        for (; j + 8 <= j1; j += 8) {
            int dd[8];
#pragma unroll
            for (int u = 0; u < 8; ++u) dd[u] = CSRS[j + u];
            float r[8][EPL];
#pragma unroll
            for (int u = 0; u < 8; ++u)
                loadrow<EPL>(Xb + (size_t)dd[u] * Fin + lane * EPL, r[u]);
#pragma unroll
            for (int u = 0; u < 8; ++u)
#pragma unroll
                for (int k = 0; k < EPL; ++k) acc[k] += r[u][k];
        }
        for (; j < j1; ++j) {
            int d = CSRS[j];
            float r[EPL];
            loadrow<EPL>(Xb + (size_t)d * Fin + lane * EPL, r);
#pragma unroll
            for (int k = 0; k < EPL; ++k) acc[k] += r[k];
        }
        float inv = 1.f / fmaxf((float)(j1 - j0), 1.f);
        float m[EPL];
        float s = 0.f;
#pragma unroll
        for (int k = 0; k < EPL; ++k) { m[k] = acc[k] * inv; s += m[k] * m[k]; }
        for (int msk = 32; msk > 0; msk >>= 1) s += __shfl_xor(s, msk, 64);
        float nrm = sqrtf(s);
        float innv = 127.f / fmaxf(nrm, 1e-8f);
        unsigned pk = 0;
#pragma unroll
        for (int k = 0; k < EPL; ++k) pk |= f2i8(m[k] * innv) << (8 * k);
        if constexpr (EPL == 4)
            *reinterpret_cast<unsigned*>(MUn + (size_t)n * Fin + lane * 4) = pk;
        else
            *reinterpret_cast<unsigned short*>(MUn + (size_t)n * Fin + lane * 2) =
                (unsigned short)pk;
        if (lane == 0) NRM[n] = nrm;
    }
}

// layers 0/1: one wave per dst node. Per edge: gather MUn[s] (int8) + XLN[s] (bf16),
// alpha = sdot4(MUn[n],MUn[s])/127^2 inline, accumulate alpha*XLN[s].
// Epilogue: + self + XB + bb, ELU -> bf16.
template<int EPLM>
__global__ void scatter_fused_elu(const unsigned char* __restrict__ MUn,
                                  const short* __restrict__ XLN,
                                  const int* __restrict__ rp_dst, const int* __restrict__ SRCd,
                                  const float* __restrict__ NRM,
                                  const short* __restrict__ XB, const float* __restrict__ bb,
                                  short* __restrict__ Yb, int N) {
    const float ISC = 1.f / 16129.f;   // 1/127^2
    int n = (blockIdx.x * blockDim.x + threadIdx.x) >> 6;
    int lane = threadIdx.x & 63;
    if (n >= N) return;
    const int FinM = EPLM * 64;
    int mn_i = loadpk<EPLM>(MUn + (size_t)n * FinM + lane * EPLM);
    int j0 = rp_dst[n], j1 = rp_dst[n + 1];
    float acc[4] = {0.f, 0.f, 0.f, 0.f};
    int j = j0;
    for (; j + 4 <= j1; j += 4) {
        int ss[4];
#pragma unroll
        for (int u = 0; u < 4; ++u) ss[u] = SRCd[j + u];
        int ms[4];
        float xl[4][4];
#pragma unroll
        for (int u = 0; u < 4; ++u)
            ms[u] = loadpk<EPLM>(MUn + (size_t)ss[u] * FinM + lane * EPLM);
#pragma unroll
        for (int u = 0; u < 4; ++u)
            loadrow<4>(XLN + (size_t)ss[u] * 256 + lane * 4, xl[u]);
        int t[4];
#pragma unroll
        for (int u = 0; u < 4; ++u) t[u] = dot4i8(mn_i, ms[u], 0);
#pragma unroll
        for (int u = 0; u < 4; ++u)
            for (int msk = 32; msk > 0; msk >>= 1) t[u] += __shfl_xor(t[u], msk, 64);
#pragma unroll
        for (int u = 0; u < 4; ++u) {
            float al = (float)t[u] * ISC;
#pragma unroll
            for (int k = 0; k < 4; ++k) acc[k] += xl[u][k] * al;
        }
    }
    for (; j < j1; ++j) {
        int s = SRCd[j];
        int ms = loadpk<EPLM>(MUn + (size_t)s * FinM + lane * EPLM);
        float xl[4];
        loadrow<4>(XLN + (size_t)s * 256 + lane * 4, xl);
        int t = dot4i8(mn_i, ms, 0);
        for (int msk = 32; msk > 0; msk >>= 1) t += __shfl_xor(t, msk, 64);
        float al = (float)t * ISC;
#pragma unroll
        for (int k = 0; k < 4; ++k) acc[k] += xl[k] * al;
    }
    float nn = NRM[n], n2 = nn * nn;
    float aself = n2 / fmaxf(n2, COS_EPS);
    float rs[4];
    loadrow<4>(XLN + (size_t)n * 256 + lane * 4, rs);
#pragma unroll
    for (int k = 0; k < 4; ++k) acc[k] += rs[k] * aself;

    float xb[4], o[4];
    loadrow<4>(XB + (size_t)n * 256 + lane * 4, xb);
    float4 bv = *reinterpret_cast<const float4*>(bb + lane * 4);
    o[0] = acc[0] + xb[0] + bv.x; o[1] = acc[1] + xb[1] + bv.y;
    o[2] = acc[2] + xb[2] + bv.z; o[3] = acc[3] + xb[3] + bv.w;
#pragma unroll
    for (int k = 0; k < 4; ++k) o[k] = (o[k] > 0.f) ? o[k] : expm1f(o[k]);
    storerow<4>(Yb + (size_t)n * 256 + lane * 4, o);
}

// layer 2: Co=40, inline int8 alpha (EPLM=4), fused log_softmax -> OUT (f32)
__global__ void scatter_final_fused(const unsigned char* __restrict__ MUn,
                                    const short* __restrict__ XLN,
                                    const int* __restrict__ rp_dst, const int* __restrict__ SRCd,
                                    const float* __restrict__ NRM, float* __restrict__ OUT,
                                    int N) {
    const float ISC = 1.f / 16129.f;
    int n = (blockIdx.x * blockDim.x + threadIdx.x) >> 6;
    int lane = threadIdx.x & 63;
    if (n >= N) return;
    bool act = lane < 40;
    int mn_i = loadpk<4>(MUn + (size_t)n * 256 + lane * 4);
    int j0 = rp_dst[n], j1 = rp_dst[n + 1];
    float acc = 0.f;
    int j = j0;
    for (; j + 4 <= j1; j += 4) {
        int ss[4];
#pragma unroll
        for (int u = 0; u < 4; ++u) ss[u] = SRCd[j + u];
        int ms[4];
        float xl[4];
#pragma unroll
        for (int u = 0; u < 4; ++u)
            ms[u] = loadpk<4>(MUn + (size_t)ss[u] * 256 + lane * 4);
#pragma unroll
        for (int u = 0; u < 4; ++u)
            xl[u] = act ? bf2f(XLN[(size_t)ss[u] * 40 + lane]) : 0.f;
        int t[4];
#pragma unroll
        for (int u = 0; u < 4; ++u) t[u] = dot4i8(mn_i, ms[u], 0);
#pragma unroll
        for (int u = 0; u < 4; ++u)
            for (int msk = 32; msk > 0; msk >>= 1) t[u] += __shfl_xor(t[u], msk, 64);
#pragma unroll
        for (int u = 0; u < 4; ++u) acc += xl[u] * ((float)t[u] * ISC);
    }
    for (; j < j1; ++j) {
        int s = SRCd[j];
        int ms = loadpk<4>(MUn + (size_t)s * 256 + lane * 4);
        float xl = act ? bf2f(XLN[(size_t)s * 40 + lane]) : 0.f;
        int t = dot4i8(mn_i, ms, 0);
        for (int msk = 32; msk > 0; msk >>= 1) t += __shfl_xor(t, msk, 64);
        acc += xl * ((float)t * ISC);
    }
    float nn = NRM[n], n2 = nn * nn;
    float aself = n2 / fmaxf(n2, COS_EPS);
    acc += (act ? bf2f(XLN[(size_t)n * 40 + lane]) : 0.f) * aself;

    float v = act ? acc : -INFINITY;
    float mx = v;
    for (int msk = 32; msk > 0; msk >>= 1) mx = fmaxf(mx, __shfl_xor(mx, msk, 64));
    float ex = act ? expf(v - mx) : 0.f;
    float se = ex;
    for (int msk = 32; msk > 0; msk >>= 1) se += __shfl_xor(se, msk, 64);
    if (act) OUT[(size_t)n * 40 + lane] = v - mx - logf(se);
}

extern "C" void kernel_launch(void* const* d_in, const int* in_sizes, int n_in,
                              void* d_out, int out_size, void* d_ws, size_t ws_size,
                              hipStream_t stream) {
    const float* x   = (const float*)d_in[0];
    const int*   ei  = (const int*)d_in[1];
    const float* W0  = (const float*)d_in[2];
    const float* g0  = (const float*)d_in[3];
    const float* b0  = (const float*)d_in[4];
    const float* B0  = (const float*)d_in[5];
    const float* bb0 = (const float*)d_in[6];
    const float* W1  = (const float*)d_in[7];
    const float* g1  = (const float*)d_in[8];
    const float* b1  = (const float*)d_in[9];
    const float* B1  = (const float*)d_in[10];
    const float* bb1 = (const float*)d_in[11];
    const float* W2  = (const float*)d_in[12];
    const float* g2  = (const float*)d_in[13];
    const float* b2  = (const float*)d_in[14];
    // d_in[15]/d_in[16] (B2 256x1, bb2): per-row constant shift, dead under log_softmax.
    float* out = (float*)d_out;

    const int N = in_sizes[0] / 128;
    const int E = in_sizes[1] / 2;
    const int* src = ei;
    const int* dst = ei + E;

    char* ws = (char*)d_ws;
    size_t off = 0;
    auto alloc = [&](size_t bytes) -> void* {
        void* p = ws + off;
        off += (bytes + 255) & ~(size_t)255;
        return p;
    };
    int* deg_src     = (int*)alloc((size_t)N * 4);
    int* deg_dst     = (int*)alloc((size_t)N * 4);
    int* rp_src      = (int*)alloc((size_t)(N + 1) * 4);
    int* rp_dst      = (int*)alloc((size_t)(N + 1) * 4);
    int* cur_src     = (int*)alloc((size_t)N * 4);
    int* cur_dst     = (int*)alloc((size_t)N * 4);
    int* bs_src      = (int*)alloc((size_t)1024 * 4);
    int* bs_dst      = (int*)alloc((size_t)1024 * 4);
    int* CSRS        = (int*)alloc((size_t)E * 4);
    int* SRCd        = (int*)alloc((size_t)E * 4);
    float* NRM       = (float*)alloc((size_t)N * 4);
    unsigned char* MUn = (unsigned char*)alloc((size_t)N * 256);  // int8 normalized means
    short* XBb       = (short*)alloc((size_t)N * 256 * 2);   // bias-path GEMM output (bf16)
    short* XLb       = (short*)alloc((size_t)N * 256 * 2);
    short* Xb_a      = (short*)alloc((size_t)N * 256 * 2);
    short* Xb_b      = (short*)alloc((size_t)N * 256 * 2);
    short* Wp0       = (short*)alloc((size_t)4 * 32 * 512 * 2);
    short* Wp1       = (short*)alloc((size_t)8 * 32 * 512 * 2);
    short* Wp2       = (short*)alloc((size_t)8 * 3 * 512 * 2);
    (void)ws_size;

    // ---- prologue: cast + pack all layer weights up front ----
    {
        int n4 = (N * 128) / 4;
        cast_bf16<<<(n4 + 255) / 256, 256, 0, stream>>>(x, Xb_a, n4);
    }
    {
        int t0 = 4 * 16 * 512;
        pack_w<<<(t0 + 255) / 256, 256, 0, stream>>>(W0, Wp0, 4, 32, 0, 16, 256);
        pack_w<<<(t0 + 255) / 256, 256, 0, stream>>>(B0, Wp0, 4, 32, 16, 16, 256);
        int t1 = 8 * 16 * 512;
        pack_w<<<(t1 + 255) / 256, 256, 0, stream>>>(W1, Wp1, 8, 32, 0, 16, 256);
        pack_w<<<(t1 + 255) / 256, 256, 0, stream>>>(B1, Wp1, 8, 32, 16, 16, 256);
        int t2 = 8 * 3 * 512;
        pack_w<<<(t2 + 255) / 256, 256, 0, stream>>>(W2, Wp2, 8, 3, 0, 3, 40);
    }

    // ---- CSR build (graph static across layers) ----
    hipMemsetAsync(deg_src, 0, (size_t)N * 4, stream);
    hipMemsetAsync(deg_dst, 0, (size_t)N * 4, stream);
    int egrid = (E + 255) / 256;
    count_deg<<<egrid, 256, 0, stream>>>(src, dst, deg_src, deg_dst, E);
    int nb = (N + 255) / 256;
    scan_phase1<<<2 * nb, 256, 0, stream>>>(deg_src, deg_dst, rp_src, rp_dst,
                                            bs_src, bs_dst, N, nb);
    scan_phase2<<<1, 256, 0, stream>>>(bs_src, bs_dst, nb, rp_src, rp_dst, N);
    scan_phase3<<<2 * nb, 256, 0, stream>>>(rp_src, rp_dst, bs_src, bs_dst,
                                            cur_src, cur_dst, N, nb);
    fill_csr<<<egrid, 256, 0, stream>>>(src, dst, cur_src, cur_dst, CSRS, SRCd, E);

    int wgridN = (N * 64 + 255) / 256;  // one wave per node (scatters)
    int ngemm  = (N + 127) / 128;       // 128 rows per GEMM block (8 waves)
    int nmu    = (N + 7) / 8;           // 8 nodes per mu block (8 waves)
    int nfat   = ngemm + nmu;

    // ---------------- layer 0: Xb_a[N,128] -> Xb_b[N,256] ----------------
    fused_gemm_mu<4, 32, 16, 1, 2><<<nfat, 512, 0, stream>>>(
        Xb_a, Wp0, XLb, XBb, g0, b0, rp_src, CSRS, MUn, NRM, N, ngemm);
    scatter_fused_elu<2><<<wgridN, 256, 0, stream>>>(MUn, XLb, rp_dst, SRCd, NRM,
                                                     XBb, bb0, Xb_b, N);

    // ---------------- layer 1: Xb_b[N,256] -> Xb_a[N,256] ----------------
    fused_gemm_mu<8, 32, 16, 1, 4><<<nfat, 512, 0, stream>>>(
        Xb_b, Wp1, XLb, XBb, g1, b1, rp_src, CSRS, MUn, NRM, N, ngemm);
    scatter_fused_elu<4><<<wgridN, 256, 0, stream>>>(MUn, XLb, rp_dst, SRCd, NRM,
                                                     XBb, bb1, Xb_a, N);

    // ---------------- layer 2: Xb_a[N,256] -> out (fused LN + log_softmax) ----------
    fused_gemm_mu<8, 3, 3, 2, 4><<<nfat, 512, 0, stream>>>(
        Xb_a, Wp2, XLb, nullptr, g2, b2, rp_src, CSRS, MUn, NRM, N, ngemm);
    scatter_final_fused<<<wgridN, 256, 0, stream>>>(MUn, XLb, rp_dst, SRCd, NRM, out, N);
}